// Round 16
// baseline (379.721 us; speedup 1.0000x reference)
//
#include <hip/hip_runtime.h>

#define DEV static __device__ __forceinline__

typedef _Float16 f16;
typedef __attribute__((ext_vector_type(8))) _Float16 f16x8;
typedef __attribute__((ext_vector_type(4))) _Float16 f16x4;
typedef __attribute__((ext_vector_type(4))) float    f32x4;

#define SCALE_QK 0.08838834764831845f   // 1/sqrt(128)

DEV float u2f(unsigned x){ union{unsigned u; float f;} c; c.u = x; return c.f; }

// ---------------------------------------------------------------------------
// async global->LDS, 16B per lane. LDS dest is wave-uniform base + lane*16.
DEV void gload16(const f16* g, f16* l){
  __builtin_amdgcn_global_load_lds((const __attribute__((address_space(1))) void*)g,
                                   (__attribute__((address_space(3))) void*)l, 16, 0, 0);
}

// ---------------------------------------------------------------------------
// NT f16 GEMM core, 3-buffer pipeline with COUNTED vmcnt (T3/T4 recipe).
template<int BM, int BN>
DEV void gemm_core3(const f16* At, int lda, const f16* Bt, int ldb, int K,
                    f32x4 (&acc)[BM/32][BN/32], f16* As, f16* Bs){
  constexpr int MR = BM / 32, NR = BN / 32;
  constexpr int ABUF = BM * 64, BBUF = BN * 64;
  static_assert(BM == 64 && BN == 64, "4 loads/wave/stage assumed");
  const int tid  = threadIdx.x;
  const int lane = tid & 63, w = tid >> 6;
  const int wr = w >> 1, wc = w & 1;
  const int lr = lane & 15, hi8 = (lane >> 4) * 8;
  const int srow = lane >> 3;
  const int sg   = (lane & 7) ^ srow;      // swizzled source granule (16B units)

  auto stage = [&](int buf, int k0){
#pragma unroll
    for (int i = 0; i < 2; ++i){
      const int ga = w + i * 4;            // A groups: w, w+4
      gload16(At + (size_t)(ga * 8 + srow) * lda + k0 + sg * 8, As + buf * ABUF + ga * 512);
    }
#pragma unroll
    for (int i = 0; i < 2; ++i){
      const int gb = w + i * 4;
      gload16(Bt + (size_t)(gb * 8 + srow) * ldb + k0 + sg * 8, Bs + buf * BBUF + gb * 512);
    }
  };

  const int nt = K / 64;
  stage(0, 0);
  if (nt > 1) stage(1, 64);
  for (int t = 0; t < nt; ++t){
    if (t + 1 < nt) asm volatile("s_waitcnt vmcnt(4)" ::: "memory");
    else            asm volatile("s_waitcnt vmcnt(0)" ::: "memory");
    __builtin_amdgcn_sched_barrier(0);
    __builtin_amdgcn_s_barrier();
    __builtin_amdgcn_sched_barrier(0);
    const f16* Ab = As + (t % 3) * ABUF;
    const f16* Bb = Bs + (t % 3) * BBUF;
#pragma unroll
    for (int kk = 0; kk < 64; kk += 32){
      f16x8 a[MR], b[NR];
#pragma unroll
      for (int mi = 0; mi < MR; ++mi){
        const int row = wr * (BM / 2) + mi * 16 + lr;
        const int col = ((((kk + hi8) >> 3) ^ (row & 7)) << 3);
        a[mi] = *reinterpret_cast<const f16x8*>(&Ab[row * 64 + col]);
      }
#pragma unroll
      for (int ni = 0; ni < NR; ++ni){
        const int row = wc * (BN / 2) + ni * 16 + lr;
        const int col = ((((kk + hi8) >> 3) ^ (row & 7)) << 3);
        b[ni] = *reinterpret_cast<const f16x8*>(&Bb[row * 64 + col]);
      }
#pragma unroll
      for (int mi = 0; mi < MR; ++mi)
#pragma unroll
        for (int ni = 0; ni < NR; ++ni)
          acc[mi][ni] = __builtin_amdgcn_mfma_f32_16x16x32_f16(a[mi], b[ni], acc[mi][ni], 0, 0, 0);
    }
    if (t + 2 < nt) stage((t + 2) % 3, (t + 2) * 64);
  }
}

// ---------------------------------------------------------------------------
__global__ __launch_bounds__(256) void kcast(const float* __restrict__ in,
                                             f16* __restrict__ out, int n){
  int i = (blockIdx.x * 256 + threadIdx.x) * 4;
  if (i < n){
    f32x4 x = *reinterpret_cast<const f32x4*>(in + i);
    f16x4 y = { (f16)x[0], (f16)x[1], (f16)x[2], (f16)x[3] };
    *reinterpret_cast<f16x4*>(out + i) = y;
  }
}

// split f32 -> hi f16 + lo f16 (x ~= hi + lo to ~22 bits)
__global__ __launch_bounds__(256) void ksplit(const float* __restrict__ in,
                                              f16* __restrict__ hi,
                                              f16* __restrict__ lo, int n4){
  int i = blockIdx.x * 256 + threadIdx.x;
  if (i < n4){
    f32x4 x = reinterpret_cast<const f32x4*>(in)[i];
    f16x4 h, l;
#pragma unroll
    for (int j = 0; j < 4; ++j){
      h[j] = (f16)x[j];
      l[j] = (f16)(x[j] - (float)h[j]);
    }
    reinterpret_cast<f16x4*>(hi)[i] = h;
    reinterpret_cast<f16x4*>(lo)[i] = l;
  }
}

// wide transpose+cast, f16x4 writes: in f32 [R][C] -> out f16 [C][R].
__global__ __launch_bounds__(256) void ktransw(const float* __restrict__ in,
                                               f16* __restrict__ out, int R, int C){
  __shared__ float t[64][65];
  const int c0 = blockIdx.x * 64, r0 = blockIdx.y * 64;
  const int tx = threadIdx.x & 63, ty = threadIdx.x >> 6;   // 64 x 4 read map
#pragma unroll
  for (int i = 0; i < 16; ++i)
    t[ty + i * 4][tx] = in[(size_t)(r0 + ty + i * 4) * C + c0 + tx];
  __syncthreads();
  const int rx = threadIdx.x & 15;          // r-quad index
  const int cy = threadIdx.x >> 4;          // 16 c-rows per pass
#pragma unroll
  for (int i = 0; i < 4; ++i){
    const int cc = cy + i * 16;
    f16x4 v = { (f16)t[4 * rx + 0][cc], (f16)t[4 * rx + 1][cc],
                (f16)t[4 * rx + 2][cc], (f16)t[4 * rx + 3][cc] };
    *reinterpret_cast<f16x4*>(&out[(size_t)(c0 + cc) * R + r0 + rx * 4]) = v;
  }
}

// fused wide transpose+cast of Wq|Wk|Wv into wqkvT (one launch), f16x4 writes
__global__ __launch_bounds__(256) void ktrans3w(const float* __restrict__ Wq,
                                                const float* __restrict__ Wk,
                                                const float* __restrict__ Wv,
                                                f16* __restrict__ wqkvT){
  __shared__ float t[64][65];
  const int bx = blockIdx.x;
  const float* in; f16* out; int C, cx;
  if (bx < 64)      { in = Wq; out = wqkvT;                        C = 4096; cx = bx; }
  else if (bx < 80) { in = Wk; out = wqkvT + (size_t)4096 * 4096;  C = 1024; cx = bx - 64; }
  else              { in = Wv; out = wqkvT + (size_t)5120 * 4096;  C = 1024; cx = bx - 80; }
  const int c0 = cx * 64, r0 = blockIdx.y * 64;
  const int tx = threadIdx.x & 63, ty = threadIdx.x >> 6;
#pragma unroll
  for (int i = 0; i < 16; ++i)
    t[ty + i * 4][tx] = in[(size_t)(r0 + ty + i * 4) * C + c0 + tx];
  __syncthreads();
  const int rx = threadIdx.x & 15;
  const int cy = threadIdx.x >> 4;
#pragma unroll
  for (int i = 0; i < 4; ++i){
    const int cc = cy + i * 16;
    f16x4 v = { (f16)t[4 * rx + 0][cc], (f16)t[4 * rx + 1][cc],
                (f16)t[4 * rx + 2][cc], (f16)t[4 * rx + 3][cc] };
    *reinterpret_cast<f16x4*>(&out[(size_t)(c0 + cc) * 4096 + r0 + rx * 4]) = v;
  }
}

// ---------------------------------------------------------------------------
// QKV projection, 64x64 tiles, counted-vmcnt 3-buffer core, XCD swizzle.
__global__ __launch_bounds__(256) void kgemm_qkv(const f16* __restrict__ A,
                                                 const f16* __restrict__ B,
                                                 float* __restrict__ qf,
                                                 float* __restrict__ kf,
                                                 f16* __restrict__ vbuf){
  __shared__ __align__(16) f16 As[3 * 64 * 64];
  __shared__ __align__(16) f16 Bs[3 * 64 * 64];
  const int orig = blockIdx.x + (blockIdx.y << 3);   // gridDim.x == 8
  const int xcd = orig & 7, idx = orig >> 3;         // idx 0..95
  const int n_t = xcd * 12 + idx % 12;               // 96 n-tiles, chunked per XCD
  const int m_t = idx / 12;                          // 8 m-tiles
  const int m0 = m_t * 64, n0 = n_t * 64;
  f32x4 acc[2][2];
#pragma unroll
  for (int i = 0; i < 2; ++i)
#pragma unroll
    for (int j = 0; j < 2; ++j){ f32x4 z = {0.f,0.f,0.f,0.f}; acc[i][j] = z; }
  gemm_core3<64,64>(A + (size_t)m0 * 4096, 4096, B + (size_t)n0 * 4096, 4096, 4096, acc, As, Bs);
  const int tid = threadIdx.x, lane = tid & 63, w = tid >> 6;
  const int wr = w >> 1, wc = w & 1, lr = lane & 15, hg = lane >> 4;
#pragma unroll
  for (int mi = 0; mi < 2; ++mi)
#pragma unroll
    for (int ni = 0; ni < 2; ++ni)
#pragma unroll
      for (int j = 0; j < 4; ++j){
        int rown = m0 + wr * 32 + mi * 16 + hg * 4 + j;
        int col  = n0 + wc * 32 + ni * 16 + lr;
        float vv = acc[mi][ni][j];
        if (col < 4096){
          int hh = col >> 7, dd = col & 127;
          qf[((size_t)hh * 512 + rown) * 128 + dd] = vv;
        } else if (col < 5120){
          int c2 = col - 4096; int hh = c2 >> 7, dd = c2 & 127;
          kf[((size_t)hh * 512 + rown) * 128 + dd] = vv;
        } else {
          int c2 = col - 5120; int hh = c2 >> 7, dd = c2 & 127;
          vbuf[((size_t)hh * 512 + rown) * 128 + dd] = (f16)vv;
        }
      }
}

// ---------------------------------------------------------------------------
// Fused RoPE + hi/lo split: reads un-roped f32 q/k, writes roped f16 hi/lo.
__global__ __launch_bounds__(256) void krope_split(const float* __restrict__ qf,
                                                   const float* __restrict__ kf,
                                                   const float* __restrict__ cosb,
                                                   const float* __restrict__ sinb,
                                                   f16* __restrict__ qh, f16* __restrict__ ql,
                                                   f16* __restrict__ kh, f16* __restrict__ kl){
  int e = blockIdx.x * 256 + threadIdx.x;
  const int QP = 32 * 512 * 64;
  const float* src; f16 *oh, *ol; int e2;
  if (e < QP){ src = qf; oh = qh; ol = ql; e2 = e; }
  else       { src = kf; oh = kh; ol = kl; e2 = e - QP; }
  int rem = e2 & 32767, n = rem >> 6, d = rem & 63;
  size_t base = ((size_t)(e2 >> 15) * 512 + n) * 128;
  float x0 = src[base + d], x1 = src[base + d + 64];
  float c = cosb[n * 128 + d], s = sinb[n * 128 + d];
  float y0 = x0 * c - x1 * s;
  float y1 = x1 * c + x0 * s;
  f16 h0 = (f16)y0; oh[base + d]      = h0; ol[base + d]      = (f16)(y0 - (float)h0);
  f16 h1 = (f16)y1; oh[base + d + 64] = h1; ol[base + d + 64] = (f16)(y1 - (float)h1);
}

// ---------------------------------------------------------------------------
// Prefix scores, 128x128 slab, 512 threads = 8 waves (2x4), 64 KB LDS:
// 2 blocks/CU x 8 waves = 4 waves/SIMD (max TLP latency hiding at this LDS).
// Per-element FMA order (k0 asc, kk asc, hh/hl/lh) unchanged -> bit-identical.
__global__ __launch_bounds__(512) void kgemm_score3(const f16* __restrict__ qh,
                                                    const f16* __restrict__ ql,
                                                    const f16* __restrict__ pkh,
                                                    const f16* __restrict__ pkl,
                                                    float* __restrict__ pscoreG,
                                                    int h0){
  __shared__ __align__(16) f16 Ah[128 * 64];
  __shared__ __align__(16) f16 Al[128 * 64];
  __shared__ __align__(16) f16 Bh[128 * 64];
  __shared__ __align__(16) f16 Bl[128 * 64];
  const int hl = blockIdx.z, h = h0 + hl, kvh = h >> 2;
  const int m0 = blockIdx.x * 128, n0 = blockIdx.y * 128;
  const f16* qhp = qh + ((size_t)h * 512 + m0) * 128;
  const f16* qlp = ql + ((size_t)h * 512 + m0) * 128;
  const f16* bhp = pkh + ((size_t)kvh * 4096 + n0) * 128;
  const f16* blp = pkl + ((size_t)kvh * 4096 + n0) * 128;
  f32x4 acc[4][2];
#pragma unroll
  for (int i = 0; i < 4; ++i)
#pragma unroll
    for (int j = 0; j < 2; ++j){ f32x4 z = {0.f,0.f,0.f,0.f}; acc[i][j] = z; }

  const int tid  = threadIdx.x;
  const int lane = tid & 63, w = tid >> 6;     // 8 waves
  const int wr = w >> 2, wc = w & 3;           // 2 x 4 wave grid
  const int lr = lane & 15, hi8 = (lane >> 4) * 8;
  const int srow = lane >> 3;
  const int sg   = (lane & 7) ^ srow;

  for (int k0 = 0; k0 < 128; k0 += 64){
    __syncthreads();
    for (int i = w; i < 16; i += 8){         // A: 16 groups (128 rows)
      const int row = i * 8 + srow;
      const size_t go = (size_t)row * 128 + k0 + sg * 8;
      gload16(qhp + go, Ah + i * 512);
      gload16(qlp + go, Al + i * 512);
    }
    for (int i = w; i < 16; i += 8){         // B: 16 groups (128 rows)
      const int row = i * 8 + srow;
      const size_t go = (size_t)row * 128 + k0 + sg * 8;
      gload16(bhp + go, Bh + i * 512);
      gload16(blp + go, Bl + i * 512);
    }
    __syncthreads();
#pragma unroll
    for (int kk = 0; kk < 64; kk += 32){
      f16x8 ah[4], al[4];
#pragma unroll
      for (int mi = 0; mi < 4; ++mi){
        const int row = wr * 64 + mi * 16 + lr;
        const int col = ((((kk + hi8) >> 3) ^ (row & 7)) << 3);
        ah[mi] = *reinterpret_cast<const f16x8*>(&Ah[row * 64 + col]);
        al[mi] = *reinterpret_cast<const f16x8*>(&Al[row * 64 + col]);
      }
#pragma unroll
      for (int ni = 0; ni < 2; ++ni){
        const int rowb = wc * 32 + ni * 16 + lr;
        const int colb = ((((kk + hi8) >> 3) ^ (rowb & 7)) << 3);
        f16x8 bh = *reinterpret_cast<const f16x8*>(&Bh[rowb * 64 + colb]);
        f16x8 bl = *reinterpret_cast<const f16x8*>(&Bl[rowb * 64 + colb]);
#pragma unroll
        for (int mi = 0; mi < 4; ++mi){
          acc[mi][ni] = __builtin_amdgcn_mfma_f32_16x16x32_f16(ah[mi], bh, acc[mi][ni], 0, 0, 0);
          acc[mi][ni] = __builtin_amdgcn_mfma_f32_16x16x32_f16(ah[mi], bl, acc[mi][ni], 0, 0, 0);
          acc[mi][ni] = __builtin_amdgcn_mfma_f32_16x16x32_f16(al[mi], bh, acc[mi][ni], 0, 0, 0);
        }
      }
    }
  }
  const int hg = lane >> 4;
#pragma unroll
  for (int mi = 0; mi < 4; ++mi)
#pragma unroll
    for (int ni = 0; ni < 2; ++ni)
#pragma unroll
      for (int j = 0; j < 4; ++j){
        int rown = m0 + wr * 64 + mi * 16 + hg * 4 + j;
        int col  = n0 + wc * 32 + ni * 16 + lr;
        pscoreG[((size_t)hl * 512 + rown) * 4096 + col] = acc[mi][ni][j] * SCALE_QK;
      }
}

// ---------------------------------------------------------------------------
// Per (h,n) row top-64 on f32 scores. Level 0: descend-from-max predicate
// counting (no atomics). Levels 1-2: byte histogram + wave-shfl suffix scan.
// PV gather reads f32 prefix_value directly.
__global__ __launch_bounds__(256) void ktopk(const unsigned* __restrict__ pscoreG,
                                             const float* __restrict__ pvf,
                                             float* __restrict__ xt,
                                             float* __restrict__ tsum,
                                             int h0){
  const int b = blockIdx.x;                 // local (h-h0)*512 + n
  const int h = h0 + (b >> 9), kvh = h >> 2;
  const size_t hn = (size_t)h * 512 + (b & 511);
  __shared__ unsigned hist[256];
  __shared__ unsigned wtot[4];
  __shared__ unsigned wmax[4];
  __shared__ unsigned wtg[4], wte[4];
  __shared__ float    wred[4];
  __shared__ int   sidx[64];
  __shared__ float sw[64];
  __shared__ float red[256];
  __shared__ unsigned scal[2];
  const int tid = threadIdx.x, lane = tid & 63, wv = tid >> 6;
  const unsigned* rowp = pscoreG + ((size_t)b << 12) + tid * 16;
  unsigned key[16];
#pragma unroll
  for (int i = 0; i < 4; ++i)
    *reinterpret_cast<uint4*>(&key[i * 4]) = *reinterpret_cast<const uint4*>(&rowp[i * 4]);
#pragma unroll
  for (int k = 0; k < 16; ++k)
    key[k] = (key[k] & 0x80000000u) ? ~key[k] : (key[k] | 0x80000000u);

  // ---- level 0: descend from the max high byte, predicate counts only
  unsigned pref, need;
  {
    unsigned mb = 0;
#pragma unroll
    for (int k = 0; k < 16; ++k) mb = max(mb, key[k] >> 24);
#pragma unroll
    for (int s2 = 32; s2 > 0; s2 >>= 1) mb = max(mb, (unsigned)__shfl_xor((int)mb, s2, 64));
    if (lane == 0) wmax[wv] = mb;
    __syncthreads();
    mb = max(max(wmax[0], wmax[1]), max(wmax[2], wmax[3]));
    __syncthreads();
    unsigned cum = 0, cur = mb;
    for (;;){
      unsigned cnt = 0, nxt = 0;
#pragma unroll
      for (int k = 0; k < 16; ++k){
        unsigned byte_ = key[k] >> 24;
        cnt += (byte_ == cur);
        if (byte_ < cur) nxt = max(nxt, byte_);
      }
#pragma unroll
      for (int s2 = 32; s2 > 0; s2 >>= 1){
        cnt += (unsigned)__shfl_xor((int)cnt, s2, 64);
        nxt  = max(nxt, (unsigned)__shfl_xor((int)nxt, s2, 64));
      }
      if (lane == 0){ wtot[wv] = cnt; wmax[wv] = nxt; }
      __syncthreads();
      unsigned tc = wtot[0] + wtot[1] + wtot[2] + wtot[3];
      unsigned tn = max(max(wmax[0], wmax[1]), max(wmax[2], wmax[3]));
      if (cum + tc >= 64u){ pref = cur; need = 64u - cum; break; }
      cum += tc; cur = tn;
      __syncthreads();
    }
    __syncthreads();
  }

  // ---- levels 1,2: byte histogram over in-bucket keys + wave-shfl scan
#pragma unroll
  for (int lvl = 1; lvl < 3; ++lvl){
    const int sh = 24 - lvl * 8;
    hist[tid] = 0; __syncthreads();
#pragma unroll
    for (int k = 0; k < 16; ++k){
      if ((key[k] >> (sh + 8)) == pref) atomicAdd(&hist[(key[k] >> sh) & 255u], 1u);
    }
    __syncthreads();
    unsigned hval = hist[tid];
    unsigned sfx = hval;
#pragma unroll
    for (int s2 = 1; s2 < 64; s2 <<= 1){
      unsigned o = __shfl_down(sfx, s2, 64);
      if (lane + s2 < 64) sfx += o;
    }
    if (lane == 0) wtot[wv] = sfx;
    __syncthreads();
    unsigned add = 0;
#pragma unroll
    for (int w2 = 0; w2 < 4; ++w2) if (w2 > wv) add += wtot[w2];
    unsigned inc = sfx + add;
    unsigned abv = inc - hval;
    if (inc >= need && abv < need){ scal[0] = (unsigned)tid; scal[1] = need - abv; }
    __syncthreads();
    pref = (pref << 8) | scal[0];
    need = scal[1];
    __syncthreads();
  }
  const unsigned P = pref;   // exact top-24-bit threshold prefix

  int cgt = 0, ceq = 0;
#pragma unroll
  for (int k = 0; k < 16; ++k){
    unsigned t24 = key[k] >> 8;
    if (t24 > P) ++cgt; else if (t24 == P) ++ceq;
  }
  unsigned pg = (unsigned)cgt, pe = (unsigned)ceq;
#pragma unroll
  for (int s2 = 1; s2 < 64; s2 <<= 1){
    unsigned og_ = __shfl_up(pg, s2, 64);
    unsigned oe_ = __shfl_up(pe, s2, 64);
    if (lane >= s2){ pg += og_; pe += oe_; }
  }
  if (lane == 63){ wtg[wv] = pg; wte[wv] = pe; }
  __syncthreads();
  unsigned addg = 0, adde = 0, totg = 0;
#pragma unroll
  for (int w2 = 0; w2 < 4; ++w2){
    totg += wtg[w2];
    if (w2 < wv){ addg += wtg[w2]; adde += wte[w2]; }
  }
  const int totgt = (int)totg;
  const int slots = 64 - totgt;
  int og = (int)(pg + addg) - cgt;
  int oe = (int)(pe + adde) - ceq;
  float wsum = 0.f;
#pragma unroll
  for (int k = 0; k < 16; ++k){
    unsigned t24 = key[k] >> 8;
    unsigned orig = (key[k] & 0x80000000u) ? (key[k] & 0x7FFFFFFFu) : ~key[k];
    if (t24 > P){
      float e = __expf(u2f(orig));
      sidx[og] = tid * 16 + k; sw[og] = e; wsum += e; ++og;
    } else if (t24 == P){
      if (oe < slots){
        float e = __expf(u2f(orig));
        sidx[totgt + oe] = tid * 16 + k; sw[totgt + oe] = e; wsum += e;
      }
      ++oe;
    }
  }
#pragma unroll
  for (int s2 = 32; s2 > 0; s2 >>= 1) wsum += __shfl_xor(wsum, s2, 64);
  if (lane == 0) wred[wv] = wsum;
  __syncthreads();
  if (tid == 0) tsum[hn] = wred[0] + wred[1] + wred[2] + wred[3];

  const int d = tid & 127, half = tid >> 7;
  float acc = 0.f;
  const float* pvb = pvf + (size_t)kvh * 4096 * 128;
  for (int i = half * 32; i < half * 32 + 32; ++i)
    acc += sw[i] * pvb[(size_t)sidx[i] * 128 + d];
  red[tid] = acc;
  __syncthreads();
  if (tid < 128) xt[hn * 128 + tid] = red[tid] + red[tid + 128];
}

// ---------------------------------------------------------------------------
// Dense causal attention per (64-row tile, head). Double-f16 3-pass QK.
__global__ __launch_bounds__(256) void kdense(const f16* __restrict__ qh,
                                              const f16* __restrict__ ql,
                                              const f16* __restrict__ kh,
                                              const f16* __restrict__ kl,
                                              const f16* __restrict__ v16,
                                              float* __restrict__ dsum,
                                              float* __restrict__ xd){
  const int ntile = blockIdx.x, h = blockIdx.y, kvh = h >> 2;
  const int n0 = ntile * 64;
  __shared__ __align__(16) f16 Ksh[64 * 136];
  __shared__ __align__(16) f16 Ksl[64 * 136];
  __shared__ __align__(16) f16 VT[128 * 72];
  __shared__ __align__(16) f16 Ps[64 * 72];
  const int tid = threadIdx.x, lane = tid & 63, w = tid >> 6;
  const int lr = lane & 15, hg = lane >> 4, hi8 = hg * 8;

  f16x8 aqh[4], aql[4];
  {
    const size_t qoff = ((size_t)h * 512 + n0 + w * 16 + lr) * 128;
#pragma unroll
    for (int c = 0; c < 4; ++c){
      aqh[c] = *reinterpret_cast<const f16x8*>(&qh[qoff + c * 32 + hi8]);
      aql[c] = *reinterpret_cast<const f16x8*>(&ql[qoff + c * 32 + hi8]);
    }
  }
  f32x4 o[8];
#pragma unroll
  for (int i = 0; i < 8; ++i){ f32x4 z = {0.f,0.f,0.f,0.f}; o[i] = z; }
  float dp[4] = {0.f, 0.f, 0.f, 0.f};

  for (int mt = 0; mt <= ntile; ++mt){
    const int m0 = mt * 64;
#pragma unroll
    for (int i = 0; i < 4; ++i){
      int vv = tid + i * 256; int row = vv >> 4, kc = (vv & 15) * 8;
      const size_t ko = ((size_t)kvh * 512 + m0 + row) * 128 + kc;
      *reinterpret_cast<f16x8*>(&Ksh[row * 136 + kc]) = *reinterpret_cast<const f16x8*>(&kh[ko]);
      *reinterpret_cast<f16x8*>(&Ksl[row * 136 + kc]) = *reinterpret_cast<const f16x8*>(&kl[ko]);
    }
#pragma unroll
    for (int i = 0; i < 8; ++i){
      int vv = tid + i * 256; int m = vv >> 5, d4 = (vv & 31) * 4;
      f16x4 x = *reinterpret_cast<const f16x4*>(&v16[((size_t)kvh * 512 + m0 + m) * 128 + d4]);
      VT[(d4 + 0) * 72 + m] = x[0];
      VT[(d4 + 1) * 72 + m] = x[1];
      VT[(d4 + 2) * 72 + m] = x[2];
      VT[(d4 + 3) * 72 + m] = x[3];
    }
    __syncthreads();
    f32x4 s[4];
#pragma unroll
    for (int j = 0; j < 4; ++j){ f32x4 z = {0.f,0.f,0.f,0.f}; s[j] = z; }
#pragma unroll
    for (int c = 0; c < 4; ++c){
#pragma unroll
      for (int j = 0; j < 4; ++j){
        f16x8 bkh = *reinterpret_cast<const f16x8*>(&Ksh[(j * 16 + lr) * 136 + c * 32 + hi8]);
        f16x8 bkl = *reinterpret_cast<const f16x8*>(&Ksl[(j * 16 + lr) * 136 + c * 32 + hi8]);
        s[j] = __builtin_amdgcn_mfma_f32_16x16x32_f16(aqh[c], bkh, s[j], 0, 0, 0);
        s[j] = __builtin_amdgcn_mfma_f32_16x16x32_f16(aqh[c], bkl, s[j], 0, 0, 0);
        s[j] = __builtin_amdgcn_mfma_f32_16x16x32_f16(aql[c], bkh, s[j], 0, 0, 0);
      }
    }
#pragma unroll
    for (int j = 0; j < 4; ++j)
#pragma unroll
      for (int r = 0; r < 4; ++r){
        int ng = n0 + w * 16 + hg * 4 + r;
        int mg = m0 + j * 16 + lr;
        float p = (mg <= ng) ? __expf(s[j][r] * SCALE_QK) : 0.f;
        dp[r] += p;
        Ps[(w * 16 + hg * 4 + r) * 72 + j * 16 + lr] = (f16)p;
      }
    __syncthreads();
#pragma unroll
    for (int kk = 0; kk < 64; kk += 32){
      f16x8 pa = *reinterpret_cast<const f16x8*>(&Ps[(w * 16 + lr) * 72 + kk + hi8]);
#pragma unroll
      for (int dt = 0; dt < 8; ++dt){
        f16x8 bv = *reinterpret_cast<const f16x8*>(&VT[(dt * 16 + lr) * 72 + kk + hi8]);
        o[dt] = __builtin_amdgcn_mfma_f32_16x16x32_f16(pa, bv, o[dt], 0, 0, 0);
      }
    }
    __syncthreads();
  }
#pragma unroll
  for (int r = 0; r < 4; ++r){
    float vs = dp[r];
#pragma unroll
    for (int off2 = 1; off2 < 16; off2 <<= 1) vs += __shfl_xor(vs, off2, 64);
    if (lr == 0) dsum[h * 512 + n0 + w * 16 + hg * 4 + r] = vs;
  }
#pragma unroll
  for (int dt = 0; dt < 8; ++dt)
#pragma unroll
    for (int r = 0; r < 4; ++r){
      int ng = n0 + w * 16 + hg * 4 + r;
      xd[((size_t)h * 512 + ng) * 128 + dt * 16 + lr] = o[dt][r];
    }
}

// ---------------------------------------------------------------------------
__global__ __launch_bounds__(256) void kcombine(const float* __restrict__ xt,
                                                const float* __restrict__ xd,
                                                const float* __restrict__ tsum,
                                                const float* __restrict__ dsum,
                                                f16* __restrict__ xh16){
  int e = blockIdx.x * 256 + threadIdx.x;    // (h*512+n)*128 + d
  int hn = e >> 7, d = e & 127;
  int h = hn >> 9, n = hn & 511;
  float denom = tsum[hn] + dsum[hn];
  float v = (xt[e] + xd[e]) / denom;
  xh16[(size_t)n * 4096 + h * 128 + d] = (f16)v;
}

// ---------------------------------------------------------------------------
// Out projection, 64x64 tiles, counted-vmcnt 3-buffer core, XCD swizzle.
__global__ __launch_bounds__(256) void kgemm_out(const f16* __restrict__ A,
                                                 const f16* __restrict__ B,
                                                 float* __restrict__ out){
  __shared__ __align__(16) f16 As[3 * 64 * 64];
  __shared__ __align__(16) f16 Bs[3 * 64 * 64];
  const int orig = blockIdx.x + (blockIdx.y << 3);   // gridDim.x == 8
  const int xcd = orig & 7, idx = orig >> 3;         // idx 0..63
  const int n_t = xcd * 8 + idx % 8;                 // 64 n-tiles, chunked
  const int m_t = idx / 8;                            // 8 m-tiles
  const int m0 = m_t * 64, n0 = n_t * 64;
  f32x4 acc[2][2];
#pragma unroll
  for (int i = 0; i < 2; ++i)
#pragma unroll
    for (int j = 0; j < 2; ++j){ f32x4 z = {0.f,0.f,0.f,0.f}; acc[i][j] = z; }
  gemm_core3<64,64>(A + (size_t)m0 * 4096, 4096, B + (size_t)n0 * 4096, 4096, 4096, acc, As, Bs);
  const int tid = threadIdx.x, lane = tid & 63, w = tid >> 6;
  const int wr = w >> 1, wc = w & 1, lr = lane & 15, hg = lane >> 4;
#pragma unroll
  for (int mi = 0; mi < 2; ++mi)
#pragma unroll
    for (int ni = 0; ni < 2; ++ni)
#pragma unroll
      for (int j = 0; j < 4; ++j){
        int rown = m0 + wr * 32 + mi * 16 + hg * 4 + j;
        int col  = n0 + wc * 32 + ni * 16 + lr;
        out[(size_t)rown * 4096 + col] = acc[mi][ni][j];
      }
}

// ---------------------------------------------------------------------------
extern "C" void kernel_launch(void* const* d_in, const int* in_sizes, int n_in,
                              void* d_out, int out_size, void* d_ws, size_t ws_size,
                              hipStream_t stream){
  (void)in_sizes; (void)n_in; (void)out_size;
  const float* hs   = (const float*)d_in[0];
  const float* cosb = (const float*)d_in[1];
  const float* sinb = (const float*)d_in[2];
  const float* pk   = (const float*)d_in[3];
  const float* pv   = (const float*)d_in[4];
  const float* Wq   = (const float*)d_in[5];
  const float* Wk   = (const float*)d_in[6];
  const float* Wv   = (const float*)d_in[7];
  const float* Wo   = (const float*)d_in[8];
  float* out = (float*)d_out;

  char* ws = (char*)d_ws;
  size_t off = 0;
  auto alloc = [&](size_t bytes) -> void* {
    void* p = ws + off; off += (bytes + 255) & ~(size_t)255; return p;
  };
  f16*  h16    = (f16*)alloc((size_t)512 * 4096 * 2);        // -> xh16 later
  f16*  wqkvT  = (f16*)alloc((size_t)6144 * 4096 * 2);       // -> woT later
  f16*  pkh    = (f16*)alloc((size_t)8 * 4096 * 128 * 2);
  f16*  pkl    = (f16*)alloc((size_t)8 * 4096 * 128 * 2);
  f16*  v16    = (f16*)alloc((size_t)8 * 512 * 128 * 2);
  f16*  qhh    = (f16*)alloc((size_t)32 * 512 * 128 * 2);
  f16*  qll    = (f16*)alloc((size_t)32 * 512 * 128 * 2);
  f16*  khh    = (f16*)alloc((size_t)8 * 512 * 128 * 2);
  f16*  kll    = (f16*)alloc((size_t)8 * 512 * 128 * 2);
  float* xd    = (float*)alloc((size_t)32 * 512 * 128 * 4);
  float* qf32  = (float*)alloc((size_t)32 * 512 * 128 * 4);  // -> xt later
  float* kf32  = (float*)alloc((size_t)8 * 512 * 128 * 4);   // -> tsum+dsum later

  f16*   woT     = wqkvT;           // after topk loop
  float* xt      = qf32;            // after krope_split
  float* tsum    = kf32;            // after krope_split
  float* dsum    = kf32 + 32 * 512;
  f16*   xh16    = h16;             // after kgemm_qkv

  const size_t bigBytes = (size_t)8 * 512 * 4096 * 4;
  const bool   big      = (ws_size >= off + bigBytes + 256);
  float* pscoreUse = big ? (float*)(ws + off) : (float*)wqkvT;
  const int hN = big ? 8 : 4;

  // casts + splits + fused QKV weight transpose (wide, f16x4 writes)
  kcast<<<2048, 256, 0, stream>>>(hs, h16, 512 * 4096);
  ksplit<<<4096, 256, 0, stream>>>(pk, pkh, pkl, 8 * 4096 * 128 / 4);
  ktrans3w<<<dim3(96, 64), 256, 0, stream>>>(Wq, Wk, Wv, wqkvT);

  kgemm_qkv<<<dim3(8, 96), 256, 0, stream>>>(h16, wqkvT, qf32, kf32, v16);
  krope_split<<<5120, 256, 0, stream>>>(qf32, kf32, cosb, sinb, qhh, qll, khh, kll);

  for (int h0 = 0; h0 < 32; h0 += hN){
    kgemm_score3<<<dim3(4, 32, hN), 512, 0, stream>>>(qhh, qll, pkh, pkl, pscoreUse, h0);
    ktopk<<<hN * 512, 256, 0, stream>>>((const unsigned*)pscoreUse, pv, xt, tsum, h0);
  }

  // wqkvT region now dead -> Wo^T (wide transpose, f16x4 writes)
  ktransw<<<dim3(64, 64), 256, 0, stream>>>(Wo, woT, 4096, 4096);

  kdense<<<dim3(8, 32), 256, 0, stream>>>(qhh, qll, khh, kll, v16, dsum, xd);
  kcombine<<<8192, 256, 0, stream>>>(xt, xd, tsum, dsum, xh16);
  kgemm_out<<<dim3(8, 64), 256, 0, stream>>>(xh16, woT, out);
}

// Round 17
// 373.994 us; speedup vs baseline: 1.0153x; 1.0153x over previous
//
#include <hip/hip_runtime.h>

#define DEV static __device__ __forceinline__

typedef _Float16 f16;
typedef __attribute__((ext_vector_type(8))) _Float16 f16x8;
typedef __attribute__((ext_vector_type(4))) _Float16 f16x4;
typedef __attribute__((ext_vector_type(4))) float    f32x4;

#define SCALE_QK 0.08838834764831845f   // 1/sqrt(128)

DEV float u2f(unsigned x){ union{unsigned u; float f;} c; c.u = x; return c.f; }

// ---------------------------------------------------------------------------
// async global->LDS, 16B per lane. LDS dest is wave-uniform base + lane*16.
DEV void gload16(const f16* g, f16* l){
  __builtin_amdgcn_global_load_lds((const __attribute__((address_space(1))) void*)g,
                                   (__attribute__((address_space(3))) void*)l, 16, 0, 0);
}

// ---------------------------------------------------------------------------
// NT f16 GEMM core, 3-buffer pipeline with COUNTED vmcnt (T3/T4 recipe).
template<int BM, int BN>
DEV void gemm_core3(const f16* At, int lda, const f16* Bt, int ldb, int K,
                    f32x4 (&acc)[BM/32][BN/32], f16* As, f16* Bs){
  constexpr int MR = BM / 32, NR = BN / 32;
  constexpr int ABUF = BM * 64, BBUF = BN * 64;
  static_assert(BM == 64 && BN == 64, "4 loads/wave/stage assumed");
  const int tid  = threadIdx.x;
  const int lane = tid & 63, w = tid >> 6;
  const int wr = w >> 1, wc = w & 1;
  const int lr = lane & 15, hi8 = (lane >> 4) * 8;
  const int srow = lane >> 3;
  const int sg   = (lane & 7) ^ srow;      // swizzled source granule (16B units)

  auto stage = [&](int buf, int k0){
#pragma unroll
    for (int i = 0; i < 2; ++i){
      const int ga = w + i * 4;            // A groups: w, w+4
      gload16(At + (size_t)(ga * 8 + srow) * lda + k0 + sg * 8, As + buf * ABUF + ga * 512);
    }
#pragma unroll
    for (int i = 0; i < 2; ++i){
      const int gb = w + i * 4;
      gload16(Bt + (size_t)(gb * 8 + srow) * ldb + k0 + sg * 8, Bs + buf * BBUF + gb * 512);
    }
  };

  const int nt = K / 64;
  stage(0, 0);
  if (nt > 1) stage(1, 64);
  for (int t = 0; t < nt; ++t){
    if (t + 1 < nt) asm volatile("s_waitcnt vmcnt(4)" ::: "memory");
    else            asm volatile("s_waitcnt vmcnt(0)" ::: "memory");
    __builtin_amdgcn_sched_barrier(0);
    __builtin_amdgcn_s_barrier();
    __builtin_amdgcn_sched_barrier(0);
    const f16* Ab = As + (t % 3) * ABUF;
    const f16* Bb = Bs + (t % 3) * BBUF;
#pragma unroll
    for (int kk = 0; kk < 64; kk += 32){
      f16x8 a[MR], b[NR];
#pragma unroll
      for (int mi = 0; mi < MR; ++mi){
        const int row = wr * (BM / 2) + mi * 16 + lr;
        const int col = ((((kk + hi8) >> 3) ^ (row & 7)) << 3);
        a[mi] = *reinterpret_cast<const f16x8*>(&Ab[row * 64 + col]);
      }
#pragma unroll
      for (int ni = 0; ni < NR; ++ni){
        const int row = wc * (BN / 2) + ni * 16 + lr;
        const int col = ((((kk + hi8) >> 3) ^ (row & 7)) << 3);
        b[ni] = *reinterpret_cast<const f16x8*>(&Bb[row * 64 + col]);
      }
#pragma unroll
      for (int mi = 0; mi < MR; ++mi)
#pragma unroll
        for (int ni = 0; ni < NR; ++ni)
          acc[mi][ni] = __builtin_amdgcn_mfma_f32_16x16x32_f16(a[mi], b[ni], acc[mi][ni], 0, 0, 0);
    }
    if (t + 2 < nt) stage((t + 2) % 3, (t + 2) * 64);
  }
}

// ---------------------------------------------------------------------------
__global__ __launch_bounds__(256) void kcast(const float* __restrict__ in,
                                             f16* __restrict__ out, int n){
  int i = (blockIdx.x * 256 + threadIdx.x) * 4;
  if (i < n){
    f32x4 x = *reinterpret_cast<const f32x4*>(in + i);
    f16x4 y = { (f16)x[0], (f16)x[1], (f16)x[2], (f16)x[3] };
    *reinterpret_cast<f16x4*>(out + i) = y;
  }
}

// split f32 -> hi f16 + lo f16 (x ~= hi + lo to ~22 bits)
__global__ __launch_bounds__(256) void ksplit(const float* __restrict__ in,
                                              f16* __restrict__ hi,
                                              f16* __restrict__ lo, int n4){
  int i = blockIdx.x * 256 + threadIdx.x;
  if (i < n4){
    f32x4 x = reinterpret_cast<const f32x4*>(in)[i];
    f16x4 h, l;
#pragma unroll
    for (int j = 0; j < 4; ++j){
      h[j] = (f16)x[j];
      l[j] = (f16)(x[j] - (float)h[j]);
    }
    reinterpret_cast<f16x4*>(hi)[i] = h;
    reinterpret_cast<f16x4*>(lo)[i] = l;
  }
}

// wide transpose+cast: float4 reads (16B/lane), f16x4 writes (8B/lane).
// in f32 [R][C] -> out f16 [C][R], 64x64 tiles.
__global__ __launch_bounds__(256) void ktransw(const float* __restrict__ in,
                                               f16* __restrict__ out, int R, int C){
  __shared__ float t[64][65];
  const int c0 = blockIdx.x * 64, r0 = blockIdx.y * 64;
  const int fx = threadIdx.x & 15;          // float4 col (16 per row)
  const int ry = threadIdx.x >> 4;          // 16 rows per pass
#pragma unroll
  for (int i = 0; i < 4; ++i){
    const int row = ry + i * 16;
    f32x4 v = *reinterpret_cast<const f32x4*>(&in[(size_t)(r0 + row) * C + c0 + fx * 4]);
    t[row][fx * 4 + 0] = v[0];
    t[row][fx * 4 + 1] = v[1];
    t[row][fx * 4 + 2] = v[2];
    t[row][fx * 4 + 3] = v[3];
  }
  __syncthreads();
  const int rx = threadIdx.x & 15;          // r-quad index
  const int cy = threadIdx.x >> 4;          // 16 c-rows per pass
#pragma unroll
  for (int i = 0; i < 4; ++i){
    const int cc = cy + i * 16;
    f16x4 v = { (f16)t[4 * rx + 0][cc], (f16)t[4 * rx + 1][cc],
                (f16)t[4 * rx + 2][cc], (f16)t[4 * rx + 3][cc] };
    *reinterpret_cast<f16x4*>(&out[(size_t)(c0 + cc) * R + r0 + rx * 4]) = v;
  }
}

// fused wide transpose+cast of Wq|Wk|Wv into wqkvT: float4 reads, f16x4 writes
__global__ __launch_bounds__(256) void ktrans3w(const float* __restrict__ Wq,
                                                const float* __restrict__ Wk,
                                                const float* __restrict__ Wv,
                                                f16* __restrict__ wqkvT){
  __shared__ float t[64][65];
  const int bx = blockIdx.x;
  const float* in; f16* out; int C, cx;
  if (bx < 64)      { in = Wq; out = wqkvT;                        C = 4096; cx = bx; }
  else if (bx < 80) { in = Wk; out = wqkvT + (size_t)4096 * 4096;  C = 1024; cx = bx - 64; }
  else              { in = Wv; out = wqkvT + (size_t)5120 * 4096;  C = 1024; cx = bx - 80; }
  const int c0 = cx * 64, r0 = blockIdx.y * 64;
  const int fx = threadIdx.x & 15;
  const int ry = threadIdx.x >> 4;
#pragma unroll
  for (int i = 0; i < 4; ++i){
    const int row = ry + i * 16;
    f32x4 v = *reinterpret_cast<const f32x4*>(&in[(size_t)(r0 + row) * C + c0 + fx * 4]);
    t[row][fx * 4 + 0] = v[0];
    t[row][fx * 4 + 1] = v[1];
    t[row][fx * 4 + 2] = v[2];
    t[row][fx * 4 + 3] = v[3];
  }
  __syncthreads();
  const int rx = threadIdx.x & 15;
  const int cy = threadIdx.x >> 4;
#pragma unroll
  for (int i = 0; i < 4; ++i){
    const int cc = cy + i * 16;
    f16x4 v = { (f16)t[4 * rx + 0][cc], (f16)t[4 * rx + 1][cc],
                (f16)t[4 * rx + 2][cc], (f16)t[4 * rx + 3][cc] };
    *reinterpret_cast<f16x4*>(&out[(size_t)(c0 + cc) * 4096 + r0 + rx * 4]) = v;
  }
}

// ---------------------------------------------------------------------------
// QKV projection, 64x64 tiles, counted-vmcnt 3-buffer core, XCD swizzle.
__global__ __launch_bounds__(256) void kgemm_qkv(const f16* __restrict__ A,
                                                 const f16* __restrict__ B,
                                                 float* __restrict__ qf,
                                                 float* __restrict__ kf,
                                                 f16* __restrict__ vbuf){
  __shared__ __align__(16) f16 As[3 * 64 * 64];
  __shared__ __align__(16) f16 Bs[3 * 64 * 64];
  const int orig = blockIdx.x + (blockIdx.y << 3);   // gridDim.x == 8
  const int xcd = orig & 7, idx = orig >> 3;         // idx 0..95
  const int n_t = xcd * 12 + idx % 12;               // 96 n-tiles, chunked per XCD
  const int m_t = idx / 12;                          // 8 m-tiles
  const int m0 = m_t * 64, n0 = n_t * 64;
  f32x4 acc[2][2];
#pragma unroll
  for (int i = 0; i < 2; ++i)
#pragma unroll
    for (int j = 0; j < 2; ++j){ f32x4 z = {0.f,0.f,0.f,0.f}; acc[i][j] = z; }
  gemm_core3<64,64>(A + (size_t)m0 * 4096, 4096, B + (size_t)n0 * 4096, 4096, 4096, acc, As, Bs);
  const int tid = threadIdx.x, lane = tid & 63, w = tid >> 6;
  const int wr = w >> 1, wc = w & 1, lr = lane & 15, hg = lane >> 4;
#pragma unroll
  for (int mi = 0; mi < 2; ++mi)
#pragma unroll
    for (int ni = 0; ni < 2; ++ni)
#pragma unroll
      for (int j = 0; j < 4; ++j){
        int rown = m0 + wr * 32 + mi * 16 + hg * 4 + j;
        int col  = n0 + wc * 32 + ni * 16 + lr;
        float vv = acc[mi][ni][j];
        if (col < 4096){
          int hh = col >> 7, dd = col & 127;
          qf[((size_t)hh * 512 + rown) * 128 + dd] = vv;
        } else if (col < 5120){
          int c2 = col - 4096; int hh = c2 >> 7, dd = c2 & 127;
          kf[((size_t)hh * 512 + rown) * 128 + dd] = vv;
        } else {
          int c2 = col - 5120; int hh = c2 >> 7, dd = c2 & 127;
          vbuf[((size_t)hh * 512 + rown) * 128 + dd] = (f16)vv;
        }
      }
}

// ---------------------------------------------------------------------------
// Fused RoPE + hi/lo split: reads un-roped f32 q/k, writes roped f16 hi/lo.
__global__ __launch_bounds__(256) void krope_split(const float* __restrict__ qf,
                                                   const float* __restrict__ kf,
                                                   const float* __restrict__ cosb,
                                                   const float* __restrict__ sinb,
                                                   f16* __restrict__ qh, f16* __restrict__ ql,
                                                   f16* __restrict__ kh, f16* __restrict__ kl){
  int e = blockIdx.x * 256 + threadIdx.x;
  const int QP = 32 * 512 * 64;
  const float* src; f16 *oh, *ol; int e2;
  if (e < QP){ src = qf; oh = qh; ol = ql; e2 = e; }
  else       { src = kf; oh = kh; ol = kl; e2 = e - QP; }
  int rem = e2 & 32767, n = rem >> 6, d = rem & 63;
  size_t base = ((size_t)(e2 >> 15) * 512 + n) * 128;
  float x0 = src[base + d], x1 = src[base + d + 64];
  float c = cosb[n * 128 + d], s = sinb[n * 128 + d];
  float y0 = x0 * c - x1 * s;
  float y1 = x1 * c + x0 * s;
  f16 h0 = (f16)y0; oh[base + d]      = h0; ol[base + d]      = (f16)(y0 - (float)h0);
  f16 h1 = (f16)y1; oh[base + d + 64] = h1; ol[base + d + 64] = (f16)(y1 - (float)h1);
}

// ---------------------------------------------------------------------------
// Prefix scores, 128x256 slab, 512 threads = 8 waves (2x4), 96 KB LDS
// (R15 measured-best config). Per-element FMA order unchanged -> bit-identical.
__global__ __launch_bounds__(512) void kgemm_score3(const f16* __restrict__ qh,
                                                    const f16* __restrict__ ql,
                                                    const f16* __restrict__ pkh,
                                                    const f16* __restrict__ pkl,
                                                    float* __restrict__ pscoreG,
                                                    int h0){
  __shared__ __align__(16) f16 Ah[128 * 64];
  __shared__ __align__(16) f16 Al[128 * 64];
  __shared__ __align__(16) f16 Bh[2 * 128 * 64];
  __shared__ __align__(16) f16 Bl[2 * 128 * 64];
  const int hl = blockIdx.z, h = h0 + hl, kvh = h >> 2;
  const int m0 = blockIdx.x * 128, n0 = blockIdx.y * 256;
  const f16* qhp = qh + ((size_t)h * 512 + m0) * 128;
  const f16* qlp = ql + ((size_t)h * 512 + m0) * 128;
  const f16* bhp = pkh + ((size_t)kvh * 4096 + n0) * 128;
  const f16* blp = pkl + ((size_t)kvh * 4096 + n0) * 128;
  f32x4 acc[4][4];
#pragma unroll
  for (int i = 0; i < 4; ++i)
#pragma unroll
    for (int j = 0; j < 4; ++j){ f32x4 z = {0.f,0.f,0.f,0.f}; acc[i][j] = z; }

  const int tid  = threadIdx.x;
  const int lane = tid & 63, w = tid >> 6;     // 8 waves
  const int wr = w >> 2, wc = w & 3;           // 2 x 4 wave grid
  const int lr = lane & 15, hi8 = (lane >> 4) * 8;
  const int srow = lane >> 3;
  const int sg   = (lane & 7) ^ srow;

  for (int k0 = 0; k0 < 128; k0 += 64){
    __syncthreads();
    for (int i = w; i < 16; i += 8){         // A: 16 groups (128 rows)
      const int row = i * 8 + srow;
      const size_t go = (size_t)row * 128 + k0 + sg * 8;
      gload16(qhp + go, Ah + i * 512);
      gload16(qlp + go, Al + i * 512);
    }
    for (int i = w; i < 32; i += 8){         // B: 32 groups (256 rows)
      const int row = i * 8 + srow;
      const size_t go = (size_t)row * 128 + k0 + sg * 8;
      gload16(bhp + go, Bh + i * 512);
      gload16(blp + go, Bl + i * 512);
    }
    __syncthreads();
#pragma unroll
    for (int kk = 0; kk < 64; kk += 32){
      f16x8 ah[4], al[4];
#pragma unroll
      for (int mi = 0; mi < 4; ++mi){
        const int row = wr * 64 + mi * 16 + lr;
        const int col = ((((kk + hi8) >> 3) ^ (row & 7)) << 3);
        ah[mi] = *reinterpret_cast<const f16x8*>(&Ah[row * 64 + col]);
        al[mi] = *reinterpret_cast<const f16x8*>(&Al[row * 64 + col]);
      }
#pragma unroll
      for (int ni = 0; ni < 4; ++ni){
        const int rowb = wc * 64 + ni * 16 + lr;           // 0..255 spans both tiles
        const int colb = ((((kk + hi8) >> 3) ^ (rowb & 7)) << 3);
        f16x8 bh = *reinterpret_cast<const f16x8*>(&Bh[rowb * 64 + colb]);
        f16x8 bl = *reinterpret_cast<const f16x8*>(&Bl[rowb * 64 + colb]);
#pragma unroll
        for (int mi = 0; mi < 4; ++mi){
          acc[mi][ni] = __builtin_amdgcn_mfma_f32_16x16x32_f16(ah[mi], bh, acc[mi][ni], 0, 0, 0);
          acc[mi][ni] = __builtin_amdgcn_mfma_f32_16x16x32_f16(ah[mi], bl, acc[mi][ni], 0, 0, 0);
          acc[mi][ni] = __builtin_amdgcn_mfma_f32_16x16x32_f16(al[mi], bh, acc[mi][ni], 0, 0, 0);
        }
      }
    }
  }
  const int hg = lane >> 4;
#pragma unroll
  for (int mi = 0; mi < 4; ++mi)
#pragma unroll
    for (int ni = 0; ni < 4; ++ni)
#pragma unroll
      for (int j = 0; j < 4; ++j){
        int rown = m0 + wr * 64 + mi * 16 + hg * 4 + j;
        int col  = n0 + wc * 64 + ni * 16 + lr;
        pscoreG[((size_t)hl * 512 + rown) * 4096 + col] = acc[mi][ni][j] * SCALE_QK;
      }
}

// ---------------------------------------------------------------------------
// Per (h,n) row top-64 on f32 scores. Level 0: descend-from-max predicate
// counting (no atomics). Levels 1-2: byte histogram + wave-shfl suffix scan.
// PV gather reads f32 prefix_value directly.
__global__ __launch_bounds__(256) void ktopk(const unsigned* __restrict__ pscoreG,
                                             const float* __restrict__ pvf,
                                             float* __restrict__ xt,
                                             float* __restrict__ tsum,
                                             int h0){
  const int b = blockIdx.x;                 // local (h-h0)*512 + n
  const int h = h0 + (b >> 9), kvh = h >> 2;
  const size_t hn = (size_t)h * 512 + (b & 511);
  __shared__ unsigned hist[256];
  __shared__ unsigned wtot[4];
  __shared__ unsigned wmax[4];
  __shared__ unsigned wtg[4], wte[4];
  __shared__ float    wred[4];
  __shared__ int   sidx[64];
  __shared__ float sw[64];
  __shared__ float red[256];
  __shared__ unsigned scal[2];
  const int tid = threadIdx.x, lane = tid & 63, wv = tid >> 6;
  const unsigned* rowp = pscoreG + ((size_t)b << 12) + tid * 16;
  unsigned key[16];
#pragma unroll
  for (int i = 0; i < 4; ++i)
    *reinterpret_cast<uint4*>(&key[i * 4]) = *reinterpret_cast<const uint4*>(&rowp[i * 4]);
#pragma unroll
  for (int k = 0; k < 16; ++k)
    key[k] = (key[k] & 0x80000000u) ? ~key[k] : (key[k] | 0x80000000u);

  // ---- level 0: descend from the max high byte, predicate counts only
  unsigned pref, need;
  {
    unsigned mb = 0;
#pragma unroll
    for (int k = 0; k < 16; ++k) mb = max(mb, key[k] >> 24);
#pragma unroll
    for (int s2 = 32; s2 > 0; s2 >>= 1) mb = max(mb, (unsigned)__shfl_xor((int)mb, s2, 64));
    if (lane == 0) wmax[wv] = mb;
    __syncthreads();
    mb = max(max(wmax[0], wmax[1]), max(wmax[2], wmax[3]));
    __syncthreads();
    unsigned cum = 0, cur = mb;
    for (;;){
      unsigned cnt = 0, nxt = 0;
#pragma unroll
      for (int k = 0; k < 16; ++k){
        unsigned byte_ = key[k] >> 24;
        cnt += (byte_ == cur);
        if (byte_ < cur) nxt = max(nxt, byte_);
      }
#pragma unroll
      for (int s2 = 32; s2 > 0; s2 >>= 1){
        cnt += (unsigned)__shfl_xor((int)cnt, s2, 64);
        nxt  = max(nxt, (unsigned)__shfl_xor((int)nxt, s2, 64));
      }
      if (lane == 0){ wtot[wv] = cnt; wmax[wv] = nxt; }
      __syncthreads();
      unsigned tc = wtot[0] + wtot[1] + wtot[2] + wtot[3];
      unsigned tn = max(max(wmax[0], wmax[1]), max(wmax[2], wmax[3]));
      if (cum + tc >= 64u){ pref = cur; need = 64u - cum; break; }
      cum += tc; cur = tn;
      __syncthreads();
    }
    __syncthreads();
  }

  // ---- levels 1,2: byte histogram over in-bucket keys + wave-shfl scan
#pragma unroll
  for (int lvl = 1; lvl < 3; ++lvl){
    const int sh = 24 - lvl * 8;
    hist[tid] = 0; __syncthreads();
#pragma unroll
    for (int k = 0; k < 16; ++k){
      if ((key[k] >> (sh + 8)) == pref) atomicAdd(&hist[(key[k] >> sh) & 255u], 1u);
    }
    __syncthreads();
    unsigned hval = hist[tid];
    unsigned sfx = hval;
#pragma unroll
    for (int s2 = 1; s2 < 64; s2 <<= 1){
      unsigned o = __shfl_down(sfx, s2, 64);
      if (lane + s2 < 64) sfx += o;
    }
    if (lane == 0) wtot[wv] = sfx;
    __syncthreads();
    unsigned add = 0;
#pragma unroll
    for (int w2 = 0; w2 < 4; ++w2) if (w2 > wv) add += wtot[w2];
    unsigned inc = sfx + add;
    unsigned abv = inc - hval;
    if (inc >= need && abv < need){ scal[0] = (unsigned)tid; scal[1] = need - abv; }
    __syncthreads();
    pref = (pref << 8) | scal[0];
    need = scal[1];
    __syncthreads();
  }
  const unsigned P = pref;   // exact top-24-bit threshold prefix

  int cgt = 0, ceq = 0;
#pragma unroll
  for (int k = 0; k < 16; ++k){
    unsigned t24 = key[k] >> 8;
    if (t24 > P) ++cgt; else if (t24 == P) ++ceq;
  }
  unsigned pg = (unsigned)cgt, pe = (unsigned)ceq;
#pragma unroll
  for (int s2 = 1; s2 < 64; s2 <<= 1){
    unsigned og_ = __shfl_up(pg, s2, 64);
    unsigned oe_ = __shfl_up(pe, s2, 64);
    if (lane >= s2){ pg += og_; pe += oe_; }
  }
  if (lane == 63){ wtg[wv] = pg; wte[wv] = pe; }
  __syncthreads();
  unsigned addg = 0, adde = 0, totg = 0;
#pragma unroll
  for (int w2 = 0; w2 < 4; ++w2){
    totg += wtg[w2];
    if (w2 < wv){ addg += wtg[w2]; adde += wte[w2]; }
  }
  const int totgt = (int)totg;
  const int slots = 64 - totgt;
  int og = (int)(pg + addg) - cgt;
  int oe = (int)(pe + adde) - ceq;
  float wsum = 0.f;
#pragma unroll
  for (int k = 0; k < 16; ++k){
    unsigned t24 = key[k] >> 8;
    unsigned orig = (key[k] & 0x80000000u) ? (key[k] & 0x7FFFFFFFu) : ~key[k];
    if (t24 > P){
      float e = __expf(u2f(orig));
      sidx[og] = tid * 16 + k; sw[og] = e; wsum += e; ++og;
    } else if (t24 == P){
      if (oe < slots){
        float e = __expf(u2f(orig));
        sidx[totgt + oe] = tid * 16 + k; sw[totgt + oe] = e; wsum += e;
      }
      ++oe;
    }
  }
#pragma unroll
  for (int s2 = 32; s2 > 0; s2 >>= 1) wsum += __shfl_xor(wsum, s2, 64);
  if (lane == 0) wred[wv] = wsum;
  __syncthreads();
  if (tid == 0) tsum[hn] = wred[0] + wred[1] + wred[2] + wred[3];

  const int d = tid & 127, half = tid >> 7;
  float acc = 0.f;
  const float* pvb = pvf + (size_t)kvh * 4096 * 128;
  for (int i = half * 32; i < half * 32 + 32; ++i)
    acc += sw[i] * pvb[(size_t)sidx[i] * 128 + d];
  red[tid] = acc;
  __syncthreads();
  if (tid < 128) xt[hn * 128 + tid] = red[tid] + red[tid + 128];
}

// ---------------------------------------------------------------------------
// Dense causal attention per (64-row tile, head). Double-f16 3-pass QK.
__global__ __launch_bounds__(256) void kdense(const f16* __restrict__ qh,
                                              const f16* __restrict__ ql,
                                              const f16* __restrict__ kh,
                                              const f16* __restrict__ kl,
                                              const f16* __restrict__ v16,
                                              float* __restrict__ dsum,
                                              float* __restrict__ xd){
  const int ntile = blockIdx.x, h = blockIdx.y, kvh = h >> 2;
  const int n0 = ntile * 64;
  __shared__ __align__(16) f16 Ksh[64 * 136];
  __shared__ __align__(16) f16 Ksl[64 * 136];
  __shared__ __align__(16) f16 VT[128 * 72];
  __shared__ __align__(16) f16 Ps[64 * 72];
  const int tid = threadIdx.x, lane = tid & 63, w = tid >> 6;
  const int lr = lane & 15, hg = lane >> 4, hi8 = hg * 8;

  f16x8 aqh[4], aql[4];
  {
    const size_t qoff = ((size_t)h * 512 + n0 + w * 16 + lr) * 128;
#pragma unroll
    for (int c = 0; c < 4; ++c){
      aqh[c] = *reinterpret_cast<const f16x8*>(&qh[qoff + c * 32 + hi8]);
      aql[c] = *reinterpret_cast<const f16x8*>(&ql[qoff + c * 32 + hi8]);
    }
  }
  f32x4 o[8];
#pragma unroll
  for (int i = 0; i < 8; ++i){ f32x4 z = {0.f,0.f,0.f,0.f}; o[i] = z; }
  float dp[4] = {0.f, 0.f, 0.f, 0.f};

  for (int mt = 0; mt <= ntile; ++mt){
    const int m0 = mt * 64;
#pragma unroll
    for (int i = 0; i < 4; ++i){
      int vv = tid + i * 256; int row = vv >> 4, kc = (vv & 15) * 8;
      const size_t ko = ((size_t)kvh * 512 + m0 + row) * 128 + kc;
      *reinterpret_cast<f16x8*>(&Ksh[row * 136 + kc]) = *reinterpret_cast<const f16x8*>(&kh[ko]);
      *reinterpret_cast<f16x8*>(&Ksl[row * 136 + kc]) = *reinterpret_cast<const f16x8*>(&kl[ko]);
    }
#pragma unroll
    for (int i = 0; i < 8; ++i){
      int vv = tid + i * 256; int m = vv >> 5, d4 = (vv & 31) * 4;
      f16x4 x = *reinterpret_cast<const f16x4*>(&v16[((size_t)kvh * 512 + m0 + m) * 128 + d4]);
      VT[(d4 + 0) * 72 + m] = x[0];
      VT[(d4 + 1) * 72 + m] = x[1];
      VT[(d4 + 2) * 72 + m] = x[2];
      VT[(d4 + 3) * 72 + m] = x[3];
    }
    __syncthreads();
    f32x4 s[4];
#pragma unroll
    for (int j = 0; j < 4; ++j){ f32x4 z = {0.f,0.f,0.f,0.f}; s[j] = z; }
#pragma unroll
    for (int c = 0; c < 4; ++c){
#pragma unroll
      for (int j = 0; j < 4; ++j){
        f16x8 bkh = *reinterpret_cast<const f16x8*>(&Ksh[(j * 16 + lr) * 136 + c * 32 + hi8]);
        f16x8 bkl = *reinterpret_cast<const f16x8*>(&Ksl[(j * 16 + lr) * 136 + c * 32 + hi8]);
        s[j] = __builtin_amdgcn_mfma_f32_16x16x32_f16(aqh[c], bkh, s[j], 0, 0, 0);
        s[j] = __builtin_amdgcn_mfma_f32_16x16x32_f16(aqh[c], bkl, s[j], 0, 0, 0);
        s[j] = __builtin_amdgcn_mfma_f32_16x16x32_f16(aql[c], bkh, s[j], 0, 0, 0);
      }
    }
#pragma unroll
    for (int j = 0; j < 4; ++j)
#pragma unroll
      for (int r = 0; r < 4; ++r){
        int ng = n0 + w * 16 + hg * 4 + r;
        int mg = m0 + j * 16 + lr;
        float p = (mg <= ng) ? __expf(s[j][r] * SCALE_QK) : 0.f;
        dp[r] += p;
        Ps[(w * 16 + hg * 4 + r) * 72 + j * 16 + lr] = (f16)p;
      }
    __syncthreads();
#pragma unroll
    for (int kk = 0; kk < 64; kk += 32){
      f16x8 pa = *reinterpret_cast<const f16x8*>(&Ps[(w * 16 + lr) * 72 + kk + hi8]);
#pragma unroll
      for (int dt = 0; dt < 8; ++dt){
        f16x8 bv = *reinterpret_cast<const f16x8*>(&VT[(dt * 16 + lr) * 72 + kk + hi8]);
        o[dt] = __builtin_amdgcn_mfma_f32_16x16x32_f16(pa, bv, o[dt], 0, 0, 0);
      }
    }
    __syncthreads();
  }
#pragma unroll
  for (int r = 0; r < 4; ++r){
    float vs = dp[r];
#pragma unroll
    for (int off2 = 1; off2 < 16; off2 <<= 1) vs += __shfl_xor(vs, off2, 64);
    if (lr == 0) dsum[h * 512 + n0 + w * 16 + hg * 4 + r] = vs;
  }
#pragma unroll
  for (int dt = 0; dt < 8; ++dt)
#pragma unroll
    for (int r = 0; r < 4; ++r){
      int ng = n0 + w * 16 + hg * 4 + r;
      xd[((size_t)h * 512 + ng) * 128 + dt * 16 + lr] = o[dt][r];
    }
}

// ---------------------------------------------------------------------------
__global__ __launch_bounds__(256) void kcombine(const float* __restrict__ xt,
                                                const float* __restrict__ xd,
                                                const float* __restrict__ tsum,
                                                const float* __restrict__ dsum,
                                                f16* __restrict__ xh16){
  int e = blockIdx.x * 256 + threadIdx.x;    // (h*512+n)*128 + d
  int hn = e >> 7, d = e & 127;
  int h = hn >> 9, n = hn & 511;
  float denom = tsum[hn] + dsum[hn];
  float v = (xt[e] + xd[e]) / denom;
  xh16[(size_t)n * 4096 + h * 128 + d] = (f16)v;
}

// ---------------------------------------------------------------------------
// Out projection, 64x64 tiles, counted-vmcnt 3-buffer core, XCD swizzle.
__global__ __launch_bounds__(256) void kgemm_out(const f16* __restrict__ A,
                                                 const f16* __restrict__ B,
                                                 float* __restrict__ out){
  __shared__ __align__(16) f16 As[3 * 64 * 64];
  __shared__ __align__(16) f16 Bs[3 * 64 * 64];
  const int orig = blockIdx.x + (blockIdx.y << 3);   // gridDim.x == 8
  const int xcd = orig & 7, idx = orig >> 3;         // idx 0..63
  const int n_t = xcd * 8 + idx % 8;                 // 64 n-tiles, chunked
  const int m_t = idx / 8;                            // 8 m-tiles
  const int m0 = m_t * 64, n0 = n_t * 64;
  f32x4 acc[2][2];
#pragma unroll
  for (int i = 0; i < 2; ++i)
#pragma unroll
    for (int j = 0; j < 2; ++j){ f32x4 z = {0.f,0.f,0.f,0.f}; acc[i][j] = z; }
  gemm_core3<64,64>(A + (size_t)m0 * 4096, 4096, B + (size_t)n0 * 4096, 4096, 4096, acc, As, Bs);
  const int tid = threadIdx.x, lane = tid & 63, w = tid >> 6;
  const int wr = w >> 1, wc = w & 1, lr = lane & 15, hg = lane >> 4;
#pragma unroll
  for (int mi = 0; mi < 2; ++mi)
#pragma unroll
    for (int ni = 0; ni < 2; ++ni)
#pragma unroll
      for (int j = 0; j < 4; ++j){
        int rown = m0 + wr * 32 + mi * 16 + hg * 4 + j;
        int col  = n0 + wc * 32 + ni * 16 + lr;
        out[(size_t)rown * 4096 + col] = acc[mi][ni][j];
      }
}

// ---------------------------------------------------------------------------
extern "C" void kernel_launch(void* const* d_in, const int* in_sizes, int n_in,
                              void* d_out, int out_size, void* d_ws, size_t ws_size,
                              hipStream_t stream){
  (void)in_sizes; (void)n_in; (void)out_size;
  const float* hs   = (const float*)d_in[0];
  const float* cosb = (const float*)d_in[1];
  const float* sinb = (const float*)d_in[2];
  const float* pk   = (const float*)d_in[3];
  const float* pv   = (const float*)d_in[4];
  const float* Wq   = (const float*)d_in[5];
  const float* Wk   = (const float*)d_in[6];
  const float* Wv   = (const float*)d_in[7];
  const float* Wo   = (const float*)d_in[8];
  float* out = (float*)d_out;

  char* ws = (char*)d_ws;
  size_t off = 0;
  auto alloc = [&](size_t bytes) -> void* {
    void* p = ws + off; off += (bytes + 255) & ~(size_t)255; return p;
  };
  f16*  h16    = (f16*)alloc((size_t)512 * 4096 * 2);        // -> xh16 later
  f16*  wqkvT  = (f16*)alloc((size_t)6144 * 4096 * 2);       // -> woT later
  f16*  pkh    = (f16*)alloc((size_t)8 * 4096 * 128 * 2);
  f16*  pkl    = (f16*)alloc((size_t)8 * 4096 * 128 * 2);
  f16*  v16    = (f16*)alloc((size_t)8 * 512 * 128 * 2);
  f16*  qhh    = (f16*)alloc((size_t)32 * 512 * 128 * 2);
  f16*  qll    = (f16*)alloc((size_t)32 * 512 * 128 * 2);
  f16*  khh    = (f16*)alloc((size_t)8 * 512 * 128 * 2);
  f16*  kll    = (f16*)alloc((size_t)8 * 512 * 128 * 2);
  float* xd    = (float*)alloc((size_t)32 * 512 * 128 * 4);
  float* qf32  = (float*)alloc((size_t)32 * 512 * 128 * 4);  // -> xt later
  float* kf32  = (float*)alloc((size_t)8 * 512 * 128 * 4);   // -> tsum+dsum later

  f16*   woT     = wqkvT;           // after topk loop
  float* xt      = qf32;            // after krope_split
  float* tsum    = kf32;            // after krope_split
  float* dsum    = kf32 + 32 * 512;
  f16*   xh16    = h16;             // after kgemm_qkv

  const size_t bigBytes = (size_t)8 * 512 * 4096 * 4;
  const bool   big      = (ws_size >= off + bigBytes + 256);
  float* pscoreUse = big ? (float*)(ws + off) : (float*)wqkvT;
  const int hN = big ? 8 : 4;

  // casts + splits + fused QKV weight transpose (float4 reads, f16x4 writes)
  kcast<<<2048, 256, 0, stream>>>(hs, h16, 512 * 4096);
  ksplit<<<4096, 256, 0, stream>>>(pk, pkh, pkl, 8 * 4096 * 128 / 4);
  ktrans3w<<<dim3(96, 64), 256, 0, stream>>>(Wq, Wk, Wv, wqkvT);

  kgemm_qkv<<<dim3(8, 96), 256, 0, stream>>>(h16, wqkvT, qf32, kf32, v16);
  krope_split<<<5120, 256, 0, stream>>>(qf32, kf32, cosb, sinb, qhh, qll, khh, kll);

  for (int h0 = 0; h0 < 32; h0 += hN){
    kgemm_score3<<<dim3(4, 16, hN), 512, 0, stream>>>(qhh, qll, pkh, pkl, pscoreUse, h0);
    ktopk<<<hN * 512, 256, 0, stream>>>((const unsigned*)pscoreUse, pv, xt, tsum, h0);
  }

  // wqkvT region now dead -> Wo^T (float4 reads, f16x4 writes)
  ktransw<<<dim3(64, 64), 256, 0, stream>>>(Wo, woT, 4096, 4096);

  kdense<<<dim3(8, 32), 256, 0, stream>>>(qhh, qll, khh, kll, v16, dsum, xd);
  kcombine<<<8192, 256, 0, stream>>>(xt, xd, tsum, dsum, xh16);
  kgemm_out<<<dim3(8, 64), 256, 0, stream>>>(xh16, woT, out);
}